// Round 6
// baseline (44.496 us; speedup 1.0000x reference)
//
#include <hip/hip_runtime.h>

// LIF recurrence: mem_t = tau*mem_{t-1} + x_t ; spike = (mem > Vth) ; hard reset.
// x: [B=16, T=32, D=65536] f32, out: spikes same shape, f32 in {0,1}.
//
// Numerics (verified round 3): harness np reference computes the chain in
// FLOAT64. Membrane carried in f64; asm-pinned v_mul_f64/v_add_f64 so no
// contraction variable. absmax == 0 with this scheme.
//
// Perf model (round 5 counters): VALUBusy 9% (not issue-bound), HBM 4.5/6.3
// TB/s (not BW-bound) -> latency-bound. Fix: raise per-wave MLP by
// prefetching 16 loads/batch into registers before computing, instead of
// unroll-8's load-consume interleave. VGPR ~50 keeps 32 waves/CU.

namespace {
constexpr int kB = 16;
constexpr int kT = 32;
constexpr int kD = 65536;
constexpr int kD2 = kD / 2;           // 32768 float2 per (b,t) row
constexpr int kBatch = 16;            // prefetch depth (t-steps)
}

typedef float f32x2 __attribute__((ext_vector_type(2)));

__device__ __forceinline__ double mul64(double a, double b) {
    double r;
    asm("v_mul_f64 %0, %1, %2" : "=v"(r) : "v"(a), "v"(b));
    return r;
}
__device__ __forceinline__ double add64(double a, double b) {
    double r;
    asm("v_add_f64 %0, %1, %2" : "=v"(r) : "v"(a), "v"(b));
    return r;
}

__global__ __launch_bounds__(256) void lif_kernel(const float* __restrict__ x,
                                                  float* __restrict__ out) {
    const int idx = blockIdx.x * blockDim.x + threadIdx.x;   // [0, kB*kD2)
    const int b  = idx >> 15;          // / kD2 (2^15)
    const int d2 = idx & (kD2 - 1);

    const f32x2* __restrict__ xin =
        reinterpret_cast<const f32x2*>(x) + (size_t)b * kT * kD2 + d2;
    f32x2* __restrict__ o =
        reinterpret_cast<f32x2*>(out) + (size_t)b * kT * kD2 + d2;

    const double tau = 0.2;            // python-float TAU, f64
    double m0 = 0.0, m1 = 0.0;

    for (int t0 = 0; t0 < kT; t0 += kBatch) {
        // Phase 1: issue all 16 loads (independent addresses) -> 16 in flight.
        f32x2 xt[kBatch];
        #pragma unroll
        for (int u = 0; u < kBatch; ++u)
            xt[u] = xin[(size_t)(t0 + u) * kD2];

        // Phase 2: serial f64 chain consumes them in order (vmcnt counts down).
        #pragma unroll
        for (int u = 0; u < kBatch; ++u) {
            // mem = rn64(rn64(tau*mem) + (double)x) — matches numpy f64 chain
            m0 = add64(mul64(tau, m0), (double)xt[u].x);
            m1 = add64(mul64(tau, m1), (double)xt[u].y);

            const bool s0 = m0 > 0.5;
            const bool s1 = m1 > 0.5;

            f32x2 s;
            s.x = s0 ? 1.f : 0.f;
            s.y = s1 ? 1.f : 0.f;

            m0 = s0 ? 0.0 : m0;        // hard reset (exact)
            m1 = s1 ? 0.0 : m1;

            // write-only output: nontemporal, don't pollute caches
            __builtin_nontemporal_store(s, &o[(size_t)(t0 + u) * kD2]);
        }
    }
}

extern "C" void kernel_launch(void* const* d_in, const int* in_sizes, int n_in,
                              void* d_out, int out_size, void* d_ws, size_t ws_size,
                              hipStream_t stream) {
    const float* x = (const float*)d_in[0];
    float* out = (float*)d_out;

    const int total = kB * kD2;              // 524288 threads
    const int block = 256;
    const int grid = total / block;          // 2048 blocks = 8/CU
    lif_kernel<<<grid, block, 0, stream>>>(x, out);
}

// Round 7
// 43.528 us; speedup vs baseline: 1.0222x; 1.0222x over previous
//
#include <hip/hip_runtime.h>

// LIF recurrence: mem_t = tau*mem_{t-1} + x_t ; spike = (mem > Vth) ; hard reset.
// x: [B=16, T=32, D=65536] f32, out: spikes same shape, f32 in {0,1}.
//
// Numerics (verified round 3): harness np reference computes the chain in
// FLOAT64. Membrane carried in f64; asm-pinned v_mul_f64/v_add_f64 so no
// contraction variable. absmax == 0 with this scheme.
//
// Perf model (rounds 5-6): BW-bound at 5.9 TB/s (94% of copy ceiling).
// FETCH = exactly half the input every round -> output write-allocation in
// the 256MB memory-side L3 evicts half the input between replays. This round:
// single-variable test of store cache-policy bits (sc0 sc1 nt) to stream
// stores past the MALL; if it works, input becomes fully L3-resident and the
// floor drops to ~writes-only (~19-25us). Null result => declared roofline.

namespace {
constexpr int kB = 16;
constexpr int kT = 32;
constexpr int kD = 65536;
constexpr int kD2 = kD / 2;           // 32768 float2 per (b,t) row
constexpr int kBatch = 16;            // prefetch depth (t-steps)
}

typedef float f32x2 __attribute__((ext_vector_type(2)));

__device__ __forceinline__ double mul64(double a, double b) {
    double r;
    asm("v_mul_f64 %0, %1, %2" : "=v"(r) : "v"(a), "v"(b));
    return r;
}
__device__ __forceinline__ double add64(double a, double b) {
    double r;
    asm("v_add_f64 %0, %1, %2" : "=v"(r) : "v"(a), "v"(b));
    return r;
}

// Streaming store: all cache-policy bits set (sc0 sc1 nt) — strongest
// "don't keep this line anywhere" hint on gfx950.
__device__ __forceinline__ void store_stream(f32x2* p, f32x2 v) {
    asm volatile("global_store_dwordx2 %0, %1, off sc0 sc1 nt"
                 :: "v"(p), "v"(v) : "memory");
}

__global__ __launch_bounds__(256) void lif_kernel(const float* __restrict__ x,
                                                  float* __restrict__ out) {
    const int idx = blockIdx.x * blockDim.x + threadIdx.x;   // [0, kB*kD2)
    const int b  = idx >> 15;          // / kD2 (2^15)
    const int d2 = idx & (kD2 - 1);

    const f32x2* __restrict__ xin =
        reinterpret_cast<const f32x2*>(x) + (size_t)b * kT * kD2 + d2;
    f32x2* __restrict__ o =
        reinterpret_cast<f32x2*>(out) + (size_t)b * kT * kD2 + d2;

    const double tau = 0.2;            // python-float TAU, f64
    double m0 = 0.0, m1 = 0.0;

    for (int t0 = 0; t0 < kT; t0 += kBatch) {
        // Phase 1: issue all 16 loads (independent addresses).
        f32x2 xt[kBatch];
        #pragma unroll
        for (int u = 0; u < kBatch; ++u)
            xt[u] = xin[(size_t)(t0 + u) * kD2];

        // Phase 2: serial f64 chain consumes them in order.
        #pragma unroll
        for (int u = 0; u < kBatch; ++u) {
            // mem = rn64(rn64(tau*mem) + (double)x) — matches numpy f64 chain
            m0 = add64(mul64(tau, m0), (double)xt[u].x);
            m1 = add64(mul64(tau, m1), (double)xt[u].y);

            const bool s0 = m0 > 0.5;
            const bool s1 = m1 > 0.5;

            f32x2 s;
            s.x = s0 ? 1.f : 0.f;
            s.y = s1 ? 1.f : 0.f;

            m0 = s0 ? 0.0 : m0;        // hard reset (exact)
            m1 = s1 ? 0.0 : m1;

            store_stream(&o[(size_t)(t0 + u) * kD2], s);
        }
    }
}

extern "C" void kernel_launch(void* const* d_in, const int* in_sizes, int n_in,
                              void* d_out, int out_size, void* d_ws, size_t ws_size,
                              hipStream_t stream) {
    const float* x = (const float*)d_in[0];
    float* out = (float*)d_out;

    const int total = kB * kD2;              // 524288 threads
    const int block = 256;
    const int grid = total / block;          // 2048 blocks = 8/CU
    lif_kernel<<<grid, block, 0, stream>>>(x, out);
}